// Round 1
// baseline (1690.492 us; speedup 1.0000x reference)
//
#include <hip/hip_runtime.h>
#include <hip/hip_bf16.h>

// Problem constants (match reference)
constexpr int IMG_ = 256;
constexpr int M_   = 1920;   // N_SHOTS * N_SAMPLES
constexpr int B_   = 64;
constexpr int MI_  = M_ * IMG_;          // 491520 elements per phase table
constexpr int IMG2 = IMG_ * IMG_;        // 65536

// ---------------------------------------------------------------------------
// Kernel 1: build separable phase tables
//   Ax[m,i] = exp(-2*pi*i * kx[m] * (i-128)) = cospi(t) + i*sinpi(t), t = -2*kx*(i-128)
// ---------------------------------------------------------------------------
__global__ __launch_bounds__(256) void phase_k(
    const float* __restrict__ samples,
    float* __restrict__ axr, float* __restrict__ axi,
    float* __restrict__ ayr, float* __restrict__ ayi) {
  int idx = blockIdx.x * 256 + threadIdx.x;
  if (idx >= MI_) return;
  int m = idx >> 8;
  int i = idx & 255;
  float g  = (float)i - 128.0f;
  float kx = samples[2 * m + 0];
  float ky = samples[2 * m + 1];
  float sx, cx, sy, cy;
  sincospif(-2.0f * kx * g, &sx, &cx);
  sincospif(-2.0f * ky * g, &sy, &cy);
  axr[idx] = cx; axi[idx] = sx;
  ayr[idx] = cy; ayi[idx] = sy;
}

// ---------------------------------------------------------------------------
// Kernel 2: fused forward NDFT + density weighting
//   K[b,m] = sum_j Ay[m,j] * (sum_i Ax[m,i] * X_b[i,j]);  kw = K * density
// Block: b = blockIdx.y, m-tile of 64 = blockIdx.x. 256 threads.
// Per j-tile (64 wide, 4 tiles): register-tiled complex GEMM T = Ax * X_b
// (4x4 complex micro-tile/thread), then multiply by Ay and reduce over j.
// ---------------------------------------------------------------------------
__global__ __launch_bounds__(256) void fwd_k(
    const float* __restrict__ xr, const float* __restrict__ xi,
    const float* __restrict__ axr, const float* __restrict__ axi,
    const float* __restrict__ ayr, const float* __restrict__ ayi,
    const float* __restrict__ density,
    float* __restrict__ kwr, float* __restrict__ kwi) {
  // LDS tiles, stride 68 (=64+4): keeps rows 16B-aligned, breaks bank aliasing
  __shared__ float asr[16 * 68], asi[16 * 68];   // A: [i-local][m-local]
  __shared__ float bsr[16 * 68], bsi[16 * 68];   // X: [i-local][j-local]

  const int t  = threadIdx.x;
  const int b  = blockIdx.y;
  const int m0 = blockIdx.x * 64;
  const int mr = t >> 4;   // 0..15 -> rows m0 + mr*4 .. +3
  const int jc = t & 15;   // 0..15 -> cols j0 + jc*4 .. +3

  const float* __restrict__ xrb = xr + (size_t)b * IMG2;
  const float* __restrict__ xib = xi + (size_t)b * IMG2;

  float kr[4] = {0.f, 0.f, 0.f, 0.f};
  float ki[4] = {0.f, 0.f, 0.f, 0.f};

  for (int jt = 0; jt < 4; ++jt) {
    const int j0 = jt * 64;
    float accr[4][4] = {};
    float acci[4][4] = {};

    for (int kt = 0; kt < 16; ++kt) {
      const int i0 = kt * 16;
      __syncthreads();
      // Stage A tile: 64 m x 16 i -> as[c(i)][r(m)]
      {
        int q = t;
#pragma unroll
        for (int rep = 0; rep < 4; ++rep, q += 256) {
          int r = q >> 4, c = q & 15;
          int g = (m0 + r) * IMG_ + i0 + c;
          asr[c * 68 + r] = axr[g];
          asi[c * 68 + r] = axi[g];
        }
      }
      // Stage X tile: 16 i x 64 j -> bs[r(i)][c(j)]
      {
        int q = t;
#pragma unroll
        for (int rep = 0; rep < 4; ++rep, q += 256) {
          int r = q >> 6, c = q & 63;
          int g = (i0 + r) * IMG_ + j0 + c;
          bsr[r * 68 + c] = xrb[g];
          bsi[r * 68 + c] = xib[g];
        }
      }
      __syncthreads();

#pragma unroll
      for (int kk = 0; kk < 16; ++kk) {
        float4 ar4 = *(const float4*)&asr[kk * 68 + mr * 4];
        float4 ai4 = *(const float4*)&asi[kk * 68 + mr * 4];
        float4 br4 = *(const float4*)&bsr[kk * 68 + jc * 4];
        float4 bi4 = *(const float4*)&bsi[kk * 68 + jc * 4];
        float arf[4] = {ar4.x, ar4.y, ar4.z, ar4.w};
        float aif[4] = {ai4.x, ai4.y, ai4.z, ai4.w};
        float brf[4] = {br4.x, br4.y, br4.z, br4.w};
        float bif[4] = {bi4.x, bi4.y, bi4.z, bi4.w};
#pragma unroll
        for (int mm = 0; mm < 4; ++mm) {
#pragma unroll
          for (int jj = 0; jj < 4; ++jj) {
            // T += Ax * X  (complex)
            accr[mm][jj] = fmaf(arf[mm], brf[jj], fmaf(-aif[mm], bif[jj], accr[mm][jj]));
            acci[mm][jj] = fmaf(arf[mm], bif[jj], fmaf(aif[mm], brf[jj], acci[mm][jj]));
          }
        }
      }
    }

    // Epilogue for this j-tile: kacc[m] += sum_j Ay[m,j] * T[m,j]
#pragma unroll
    for (int mm = 0; mm < 4; ++mm) {
      int m = m0 + mr * 4 + mm;
      float4 yr4 = *(const float4*)&ayr[m * IMG_ + j0 + jc * 4];
      float4 yi4 = *(const float4*)&ayi[m * IMG_ + j0 + jc * 4];
      float yrf[4] = {yr4.x, yr4.y, yr4.z, yr4.w};
      float yif[4] = {yi4.x, yi4.y, yi4.z, yi4.w};
#pragma unroll
      for (int jj = 0; jj < 4; ++jj) {
        kr[mm] = fmaf(yrf[jj], accr[mm][jj], fmaf(-yif[jj], acci[mm][jj], kr[mm]));
        ki[mm] = fmaf(yrf[jj], acci[mm][jj], fmaf(yif[jj], accr[mm][jj], ki[mm]));
      }
    }
  }

  // Reduce over the 16 jc lanes (consecutive lanes within the wave)
#pragma unroll
  for (int mm = 0; mm < 4; ++mm) {
#pragma unroll
    for (int off = 8; off >= 1; off >>= 1) {
      kr[mm] += __shfl_xor(kr[mm], off, 16);
      ki[mm] += __shfl_xor(ki[mm], off, 16);
    }
  }
  if (jc == 0) {
#pragma unroll
    for (int mm = 0; mm < 4; ++mm) {
      int m = m0 + mr * 4 + mm;
      float d = density[m];
      kwr[b * M_ + m] = kr[mm] * d;
      kwi[b * M_ + m] = ki[mm] * d;
    }
  }
}

// ---------------------------------------------------------------------------
// Kernel 3: adjoint NDFT
//   adj[b,i,j] = (1/IMG^2) * sum_m conj(Ax[m,i]) * kw[b,m] * conj(Ay[m,j])
// Block: b = blockIdx.z, i-tile = blockIdx.x, j-tile = blockIdx.y (64x64).
// Complex GEMM with K-dim = M = 1920, staged in 16-row tiles; W = kw*conj(Ay)
// computed during staging. Output written interleaved re/im (float4 stores).
// ---------------------------------------------------------------------------
__global__ __launch_bounds__(256) void adj_k(
    const float* __restrict__ axr, const float* __restrict__ axi,
    const float* __restrict__ ayr, const float* __restrict__ ayi,
    const float* __restrict__ kwr, const float* __restrict__ kwi,
    float* __restrict__ out) {
  __shared__ float asr[16 * 68], asi[16 * 68];   // conj(Ax): [m-local][i-local]
  __shared__ float wsr[16 * 68], wsi[16 * 68];   // kw*conj(Ay): [m-local][j-local]

  const int t  = threadIdx.x;
  const int b  = blockIdx.z;
  const int i0 = blockIdx.x * 64;
  const int j0 = blockIdx.y * 64;
  const int ir = t >> 4;   // rows i0 + ir*4 ..
  const int jc = t & 15;   // cols j0 + jc*4 ..

  float accr[4][4] = {};
  float acci[4][4] = {};

  for (int mt = 0; mt < M_ / 16; ++mt) {
    const int m0 = mt * 16;
    __syncthreads();
    {
      int q = t;
#pragma unroll
      for (int rep = 0; rep < 4; ++rep, q += 256) {
        int r = q >> 6, c = q & 63;
        int g = (m0 + r) * IMG_ + i0 + c;
        asr[r * 68 + c] = axr[g];
        asi[r * 68 + c] = -axi[g];        // conjugate
      }
      q = t;
#pragma unroll
      for (int rep = 0; rep < 4; ++rep, q += 256) {
        int r = q >> 6, c = q & 63;
        float wr = kwr[b * M_ + m0 + r];
        float wi = kwi[b * M_ + m0 + r];
        int g = (m0 + r) * IMG_ + j0 + c;
        float yr = ayr[g], yi = ayi[g];
        // kw * conj(Ay) = (wr*yr + wi*yi) + i*(wi*yr - wr*yi)
        wsr[r * 68 + c] = fmaf(wr, yr, wi * yi);
        wsi[r * 68 + c] = fmaf(wi, yr, -(wr * yi));
      }
    }
    __syncthreads();

#pragma unroll
    for (int kk = 0; kk < 16; ++kk) {
      float4 ar4 = *(const float4*)&asr[kk * 68 + ir * 4];
      float4 ai4 = *(const float4*)&asi[kk * 68 + ir * 4];
      float4 wr4 = *(const float4*)&wsr[kk * 68 + jc * 4];
      float4 wi4 = *(const float4*)&wsi[kk * 68 + jc * 4];
      float arf[4] = {ar4.x, ar4.y, ar4.z, ar4.w};
      float aif[4] = {ai4.x, ai4.y, ai4.z, ai4.w};
      float wrf[4] = {wr4.x, wr4.y, wr4.z, wr4.w};
      float wif[4] = {wi4.x, wi4.y, wi4.z, wi4.w};
#pragma unroll
      for (int ii = 0; ii < 4; ++ii) {
#pragma unroll
        for (int jj = 0; jj < 4; ++jj) {
          accr[ii][jj] = fmaf(arf[ii], wrf[jj], fmaf(-aif[ii], wif[jj], accr[ii][jj]));
          acci[ii][jj] = fmaf(arf[ii], wif[jj], fmaf(aif[ii], wrf[jj], acci[ii][jj]));
        }
      }
    }
  }

  const float s = 1.0f / (float)IMG2;
#pragma unroll
  for (int ii = 0; ii < 4; ++ii) {
    int i = i0 + ir * 4 + ii;
    float* dst = out + ((size_t)(b * IMG_ + i) * IMG_ + j0 + jc * 4) * 2;
    float4 lo = make_float4(accr[ii][0] * s, acci[ii][0] * s,
                            accr[ii][1] * s, acci[ii][1] * s);
    float4 hi = make_float4(accr[ii][2] * s, acci[ii][2] * s,
                            accr[ii][3] * s, acci[ii][3] * s);
    *(float4*)(dst + 0) = lo;
    *(float4*)(dst + 4) = hi;
  }
}

// ---------------------------------------------------------------------------
// Launch
// ---------------------------------------------------------------------------
extern "C" void kernel_launch(void* const* d_in, const int* in_sizes, int n_in,
                              void* d_out, int out_size, void* d_ws, size_t ws_size,
                              hipStream_t stream) {
  (void)in_sizes; (void)n_in; (void)out_size; (void)ws_size;

  const float* xr      = (const float*)d_in[0];  // (B,1,256,256)
  const float* xi      = (const float*)d_in[1];
  const float* samples = (const float*)d_in[2];  // (M,2)
  const float* density = (const float*)d_in[3];  // (M,)
  float* out = (float*)d_out;                    // (B,1,256,256,2)

  // Workspace layout (floats): 4 phase tables + complex kw
  float* ws  = (float*)d_ws;
  float* axr = ws + 0 * MI_;
  float* axi = ws + 1 * MI_;
  float* ayr = ws + 2 * MI_;
  float* ayi = ws + 3 * MI_;
  float* kwr = ws + 4 * MI_;
  float* kwi = kwr + B_ * M_;
  // total: 4*491520 + 2*122880 floats = 8.85 MB

  phase_k<<<(MI_ + 255) / 256, 256, 0, stream>>>(samples, axr, axi, ayr, ayi);
  fwd_k<<<dim3(M_ / 64, B_), 256, 0, stream>>>(xr, xi, axr, axi, ayr, ayi,
                                               density, kwr, kwi);
  adj_k<<<dim3(IMG_ / 64, IMG_ / 64, B_), 256, 0, stream>>>(axr, axi, ayr, ayi,
                                                            kwr, kwi, out);
}

// Round 2
// 288.025 us; speedup vs baseline: 5.8693x; 5.8693x over previous
//
#include <hip/hip_runtime.h>
#include <hip/hip_bf16.h>
#include <hip/hip_fp16.h>

// Problem constants (match reference)
constexpr int IMG_ = 256;
constexpr int M_   = 1920;   // N_SHOTS * N_SAMPLES
constexpr int B_   = 64;
constexpr int MI_  = M_ * IMG_;          // 491520 elements per phase table
constexpr int IMG2 = IMG_ * IMG_;        // 65536

typedef _Float16 half8 __attribute__((ext_vector_type(8)));
typedef float    floatx4 __attribute__((ext_vector_type(4)));

// ---------------------------------------------------------------------------
// Phase tables, natural layout [m][i] (f16): Ax = exp(-2i*pi*kx*g), Ay likewise
// ---------------------------------------------------------------------------
__global__ __launch_bounds__(256) void phase1_k(
    const float* __restrict__ samples,
    _Float16* __restrict__ axh_r, _Float16* __restrict__ axh_i,
    _Float16* __restrict__ ayh_r, _Float16* __restrict__ ayh_i) {
  int idx = blockIdx.x * 256 + threadIdx.x;
  if (idx >= MI_) return;
  int m = idx >> 8;
  int i = idx & 255;
  float g  = (float)i - 128.0f;
  float kx = samples[2 * m + 0];
  float ky = samples[2 * m + 1];
  float sx, cx, sy, cy;
  sincospif(-2.0f * kx * g, &sx, &cx);
  sincospif(-2.0f * ky * g, &sy, &cy);
  axh_r[idx] = (_Float16)cx; axh_i[idx] = (_Float16)sx;
  ayh_r[idx] = (_Float16)cy; ayh_i[idx] = (_Float16)sy;
}

// Transposed, pre-conjugated tables [i][m] (f16) for the adjoint pass.
__global__ __launch_bounds__(256) void phase2_k(
    const float* __restrict__ samples,
    _Float16* __restrict__ axtc_r, _Float16* __restrict__ axtc_i,
    _Float16* __restrict__ aytc_r, _Float16* __restrict__ aytc_i) {
  int m = blockIdx.x * 256 + threadIdx.x;
  if (m >= M_) return;
  int i = blockIdx.y;
  float g  = (float)i - 128.0f;
  float kx = samples[2 * m + 0];
  float ky = samples[2 * m + 1];
  float sx, cx, sy, cy;
  sincospif(-2.0f * kx * g, &sx, &cx);
  sincospif(-2.0f * ky * g, &sy, &cy);
  int o = i * M_ + m;
  axtc_r[o] = (_Float16)cx; axtc_i[o] = (_Float16)(-sx);  // conj(Ax)^T
  aytc_r[o] = (_Float16)cy; aytc_i[o] = (_Float16)(-sy);  // conj(Ay)^T
}

// ---------------------------------------------------------------------------
// X transpose + f16 convert: xth[b][j][i] = x[b][i][j]  (B-operand for fwd)
// ---------------------------------------------------------------------------
__global__ __launch_bounds__(256) void xt_k(
    const float* __restrict__ xr, const float* __restrict__ xi,
    _Float16* __restrict__ xth_r, _Float16* __restrict__ xth_i) {
  __shared__ float tr[32][33], ti[32][33];
  const int t = threadIdx.x;
  const int b = blockIdx.z;
  const int i0 = blockIdx.x * 32, j0 = blockIdx.y * 32;
  const int r = t >> 5, c = t & 31;
#pragma unroll
  for (int k = 0; k < 4; ++k) {
    int row = r + k * 8;
    tr[row][c] = xr[(size_t)b * IMG2 + (i0 + row) * IMG_ + j0 + c];
    ti[row][c] = xi[(size_t)b * IMG2 + (i0 + row) * IMG_ + j0 + c];
  }
  __syncthreads();
#pragma unroll
  for (int k = 0; k < 4; ++k) {
    int row = r + k * 8;
    xth_r[(size_t)b * IMG2 + (j0 + row) * IMG_ + i0 + c] = (_Float16)tr[c][row];
    xth_i[(size_t)b * IMG2 + (j0 + row) * IMG_ + i0 + c] = (_Float16)ti[c][row];
  }
}

// ---------------------------------------------------------------------------
// Forward NDFT via f16 MFMA + fused Ay-weighted j-reduction + density
//   kspace[b,m] = sum_j Ay[m,j] * (sum_i Ax[m,i] * X_b[i,j]);  kw = K*density
// Grid (30, 64); block 256 = 4 waves; wave w owns m-strip m0+16w.
// ---------------------------------------------------------------------------
__global__ __launch_bounds__(256) void fwd_k(
    const _Float16* __restrict__ axh_r, const _Float16* __restrict__ axh_i,
    const _Float16* __restrict__ ayh_r, const _Float16* __restrict__ ayh_i,
    const _Float16* __restrict__ xth_r, const _Float16* __restrict__ xth_i,
    const float* __restrict__ density,
    _Float16* __restrict__ kwh_r, _Float16* __restrict__ kwh_i) {
  // stride 40 halfs: 16B-aligned rows, non-pow2 banking
  __shared__ _Float16 asr[64 * 40], asi[64 * 40];
  __shared__ _Float16 bsr[64 * 40], bsi[64 * 40];

  const int t = threadIdx.x;
  const int w = t >> 6;
  const int l = t & 63;
  const int lr = l & 15;   // A-frag row / C col
  const int q  = l >> 4;   // quad
  const int b  = blockIdx.y;
  const int m0 = blockIdx.x * 64;
  const _Float16* __restrict__ xrb = xth_r + (size_t)b * IMG2;
  const _Float16* __restrict__ xib = xth_i + (size_t)b * IMG2;

  float kr[4] = {0.f, 0.f, 0.f, 0.f};
  float ki[4] = {0.f, 0.f, 0.f, 0.f};
  const floatx4 z4 = {0.f, 0.f, 0.f, 0.f};

  for (int jc = 0; jc < 4; ++jc) {
    const int j0 = jc * 64;
    floatx4 accr[4] = {z4, z4, z4, z4};
    floatx4 acci[4] = {z4, z4, z4, z4};

    for (int kt = 0; kt < 8; ++kt) {
      const int i0 = kt * 32;
      __syncthreads();
#pragma unroll
      for (int p = 0; p < 2; ++p) {
        int slot = t + p * 256;
        int row = slot >> 3, seg = slot & 7;
        *(uint2*)&asr[row * 40 + seg * 4] = *(const uint2*)&axh_r[(m0 + row) * IMG_ + i0 + seg * 4];
        *(uint2*)&asi[row * 40 + seg * 4] = *(const uint2*)&axh_i[(m0 + row) * IMG_ + i0 + seg * 4];
        *(uint2*)&bsr[row * 40 + seg * 4] = *(const uint2*)&xrb[(j0 + row) * IMG_ + i0 + seg * 4];
        *(uint2*)&bsi[row * 40 + seg * 4] = *(const uint2*)&xib[(j0 + row) * IMG_ + i0 + seg * 4];
      }
      __syncthreads();

      half8 ar = *(const half8*)&asr[(w * 16 + lr) * 40 + q * 8];
      half8 ai = *(const half8*)&asi[(w * 16 + lr) * 40 + q * 8];
      half8 nai = -ai;
#pragma unroll
      for (int jt = 0; jt < 4; ++jt) {
        half8 br = *(const half8*)&bsr[(jt * 16 + lr) * 40 + q * 8];
        half8 bi = *(const half8*)&bsi[(jt * 16 + lr) * 40 + q * 8];
        accr[jt] = __builtin_amdgcn_mfma_f32_16x16x32_f16(ar,  br, accr[jt], 0, 0, 0);
        accr[jt] = __builtin_amdgcn_mfma_f32_16x16x32_f16(nai, bi, accr[jt], 0, 0, 0);
        acci[jt] = __builtin_amdgcn_mfma_f32_16x16x32_f16(ar,  bi, acci[jt], 0, 0, 0);
        acci[jt] = __builtin_amdgcn_mfma_f32_16x16x32_f16(ai,  br, acci[jt], 0, 0, 0);
      }
    }

    // Epilogue: kacc[m] += sum_j Ay[m,j] * T[m,j]  (C layout: col=lr, row=q*4+reg)
#pragma unroll
    for (int jt = 0; jt < 4; ++jt) {
      int j = j0 + jt * 16 + lr;
#pragma unroll
      for (int reg = 0; reg < 4; ++reg) {
        int m = m0 + w * 16 + q * 4 + reg;
        float yr = (float)ayh_r[m * IMG_ + j];
        float yi = (float)ayh_i[m * IMG_ + j];
        float tr = accr[jt][reg], ti = acci[jt][reg];
        kr[reg] = fmaf(yr, tr, fmaf(-yi, ti, kr[reg]));
        ki[reg] = fmaf(yr, ti, fmaf(yi, tr, ki[reg]));
      }
    }
  }

  // Reduce across the 16 lanes of each quad-row group
#pragma unroll
  for (int reg = 0; reg < 4; ++reg) {
#pragma unroll
    for (int off = 1; off < 16; off <<= 1) {
      kr[reg] += __shfl_xor(kr[reg], off);
      ki[reg] += __shfl_xor(ki[reg], off);
    }
  }
  if (lr == 0) {
#pragma unroll
    for (int reg = 0; reg < 4; ++reg) {
      int m = m0 + w * 16 + q * 4 + reg;
      float d = density[m];
      kwh_r[b * M_ + m] = (_Float16)(kr[reg] * d);
      kwh_i[b * M_ + m] = (_Float16)(ki[reg] * d);
    }
  }
}

// ---------------------------------------------------------------------------
// Adjoint NDFT via f16 MFMA:
//   out[b,i,j] = (1/IMG^2) sum_m conj(Ax)[m,i] * kw[b,m] * conj(Ay)[m,j]
// A-operand = axtc (pre-conj, [i][m]); B = kw*conj(Ay) computed during staging.
// Grid (4, 4, 64); block 256 = 4 waves; wave w owns i-strip i0+16w.
// ---------------------------------------------------------------------------
__global__ __launch_bounds__(256) void adj_k(
    const _Float16* __restrict__ axtc_r, const _Float16* __restrict__ axtc_i,
    const _Float16* __restrict__ aytc_r, const _Float16* __restrict__ aytc_i,
    const _Float16* __restrict__ kwh_r, const _Float16* __restrict__ kwh_i,
    float* __restrict__ out) {
  __shared__ _Float16 asr[64 * 40], asi[64 * 40];
  __shared__ _Float16 wsr[64 * 40], wsi[64 * 40];

  const int t = threadIdx.x;
  const int w = t >> 6;
  const int l = t & 63;
  const int lr = l & 15;
  const int q  = l >> 4;
  const int b  = blockIdx.z;
  const int i0 = blockIdx.x * 64;
  const int j0 = blockIdx.y * 64;

  const floatx4 z4 = {0.f, 0.f, 0.f, 0.f};
  floatx4 accr[4] = {z4, z4, z4, z4};
  floatx4 acci[4] = {z4, z4, z4, z4};

  for (int mt = 0; mt < M_ / 32; ++mt) {
    const int m0 = mt * 32;
    __syncthreads();
    // Stage A: conj(Ax)^T tile, 64 i-rows x 32 m
#pragma unroll
    for (int p = 0; p < 2; ++p) {
      int slot = t + p * 256;
      int row = slot >> 3, seg = slot & 7;
      *(uint2*)&asr[row * 40 + seg * 4] = *(const uint2*)&axtc_r[(i0 + row) * M_ + m0 + seg * 4];
      *(uint2*)&asi[row * 40 + seg * 4] = *(const uint2*)&axtc_i[(i0 + row) * M_ + m0 + seg * 4];
    }
    // Stage W = kw * conj(Ay), 64 j-rows x 32 m, packed-f16 math
    {
      int row = t >> 2, seg = t & 3;
      const __half2* ay_r = (const __half2*)&aytc_r[(j0 + row) * M_ + m0 + seg * 8];
      const __half2* ay_i = (const __half2*)&aytc_i[(j0 + row) * M_ + m0 + seg * 8];
      const __half2* kw_r = (const __half2*)&kwh_r[b * M_ + m0 + seg * 8];
      const __half2* kw_i = (const __half2*)&kwh_i[b * M_ + m0 + seg * 8];
      __half2 wr[4], wi[4];
#pragma unroll
      for (int e = 0; e < 4; ++e) {
        __half2 yr = ay_r[e], yi = ay_i[e], cr = kw_r[e], ci = kw_i[e];
        wr[e] = __hsub2(__hmul2(cr, yr), __hmul2(ci, yi));
        wi[e] = __hfma2(cr, yi, __hmul2(ci, yr));
      }
      *(uint4*)&wsr[row * 40 + seg * 8] = *(uint4*)wr;
      *(uint4*)&wsi[row * 40 + seg * 8] = *(uint4*)wi;
    }
    __syncthreads();

    half8 ar = *(const half8*)&asr[(w * 16 + lr) * 40 + q * 8];
    half8 ai = *(const half8*)&asi[(w * 16 + lr) * 40 + q * 8];
    half8 nai = -ai;
#pragma unroll
    for (int jt = 0; jt < 4; ++jt) {
      half8 br = *(const half8*)&wsr[(jt * 16 + lr) * 40 + q * 8];
      half8 bi = *(const half8*)&wsi[(jt * 16 + lr) * 40 + q * 8];
      accr[jt] = __builtin_amdgcn_mfma_f32_16x16x32_f16(ar,  br, accr[jt], 0, 0, 0);
      accr[jt] = __builtin_amdgcn_mfma_f32_16x16x32_f16(nai, bi, accr[jt], 0, 0, 0);
      acci[jt] = __builtin_amdgcn_mfma_f32_16x16x32_f16(ar,  bi, acci[jt], 0, 0, 0);
      acci[jt] = __builtin_amdgcn_mfma_f32_16x16x32_f16(ai,  br, acci[jt], 0, 0, 0);
    }
  }

  const float s = 1.0f / (float)IMG2;
#pragma unroll
  for (int jt = 0; jt < 4; ++jt) {
    int jg = j0 + jt * 16 + lr;
#pragma unroll
    for (int reg = 0; reg < 4; ++reg) {
      int ig = i0 + w * 16 + q * 4 + reg;
      float2 v = make_float2(accr[jt][reg] * s, acci[jt][reg] * s);
      *(float2*)&out[((size_t)(b * IMG_ + ig) * IMG_ + jg) * 2] = v;
    }
  }
}

// ---------------------------------------------------------------------------
// Launch
// ---------------------------------------------------------------------------
extern "C" void kernel_launch(void* const* d_in, const int* in_sizes, int n_in,
                              void* d_out, int out_size, void* d_ws, size_t ws_size,
                              hipStream_t stream) {
  (void)in_sizes; (void)n_in; (void)out_size; (void)ws_size;

  const float* xr      = (const float*)d_in[0];
  const float* xi      = (const float*)d_in[1];
  const float* samples = (const float*)d_in[2];
  const float* density = (const float*)d_in[3];
  float* out = (float*)d_out;

  // ws: 10 f16 arrays, 8.36 MB total
  _Float16* f = (_Float16*)d_ws;
  _Float16* axh_r  = f + 0 * MI_;
  _Float16* axh_i  = f + 1 * MI_;
  _Float16* ayh_r  = f + 2 * MI_;
  _Float16* ayh_i  = f + 3 * MI_;
  _Float16* axtc_r = f + 4 * MI_;
  _Float16* axtc_i = f + 5 * MI_;
  _Float16* aytc_r = f + 6 * MI_;
  _Float16* aytc_i = f + 7 * MI_;
  _Float16* kwh_r  = f + 8 * MI_;
  _Float16* kwh_i  = kwh_r + B_ * M_;

  // X^T (f16) parked in d_out; fully consumed by fwd_k before adj_k overwrites.
  _Float16* xth_r = (_Float16*)d_out;
  _Float16* xth_i = xth_r + (size_t)B_ * IMG2;

  phase1_k<<<(MI_ + 255) / 256, 256, 0, stream>>>(samples, axh_r, axh_i, ayh_r, ayh_i);
  phase2_k<<<dim3(8, IMG_), 256, 0, stream>>>(samples, axtc_r, axtc_i, aytc_r, aytc_i);
  xt_k<<<dim3(8, 8, B_), 256, 0, stream>>>(xr, xi, xth_r, xth_i);
  fwd_k<<<dim3(M_ / 64, B_), 256, 0, stream>>>(axh_r, axh_i, ayh_r, ayh_i,
                                               xth_r, xth_i, density, kwh_r, kwh_i);
  adj_k<<<dim3(4, 4, B_), 256, 0, stream>>>(axtc_r, axtc_i, aytc_r, aytc_i,
                                            kwh_r, kwh_i, out);
}